// Round 1
// baseline (3052.856 us; speedup 1.0000x reference)
//
#include <hip/hip_runtime.h>

#define NB 8        // batch
#define DIMC 128
#define KNBR 8

// ---------------- KNN: per-thread top-8 (optionally excluding self) ----------------
#define KT 512
template<bool EXCL>
__global__ void knn_kernel(const float* __restrict__ ref, const float* __restrict__ qry,
                           int Nr, int Nq, int* __restrict__ idx_out) {
  __shared__ float sx[KT], sy[KT], sz[KT], sr2[KT];
  int b = blockIdx.y;
  int qi = blockIdx.x * blockDim.x + threadIdx.x;
  const float* rb = ref + (size_t)b * 3 * Nr;
  const float* qb = qry + (size_t)b * 3 * Nq;
  float qx = qb[qi], qy = qb[Nq + qi], qz = qb[2 * Nq + qi];
  float q2 = qx * qx + qy * qy + qz * qz;
  float bd[KNBR]; int bi[KNBR];
#pragma unroll
  for (int t = 0; t < KNBR; t++) { bd[t] = 3.4e38f; bi[t] = 0; }
  for (int tile = 0; tile < Nr; tile += KT) {
    int cnt = min(KT, Nr - tile);
    __syncthreads();
    for (int j = threadIdx.x; j < cnt; j += blockDim.x) {
      float rx = rb[tile + j], ry = rb[Nr + tile + j], rz = rb[2 * Nr + tile + j];
      sx[j] = rx; sy[j] = ry; sz[j] = rz; sr2[j] = rx * rx + ry * ry + rz * rz;
    }
    __syncthreads();
    for (int j = 0; j < cnt; j++) {
      int gj = tile + j;
      if (EXCL && gj == qi) continue;
      float d = q2 - 2.f * (qx * sx[j] + qy * sy[j] + qz * sz[j]) + sr2[j];
      if (d < bd[KNBR - 1]) {
        bd[KNBR - 1] = d; bi[KNBR - 1] = gj;
#pragma unroll
        for (int t = KNBR - 1; t > 0; t--)
          if (bd[t] < bd[t - 1]) {
            float td = bd[t]; bd[t] = bd[t - 1]; bd[t - 1] = td;
            int ti = bi[t]; bi[t] = bi[t - 1]; bi[t - 1] = ti;
          }
      }
    }
  }
  int* o = idx_out + ((size_t)b * Nq + qi) * KNBR;
#pragma unroll
  for (int t = 0; t < KNBR; t++) o[t] = bi[t];
}

// ---------------- featurenet conv0: W0(128x3) applied to (gathered xyz - center) ----------------
__global__ void conv0_kernel(const float* __restrict__ xyz, const int* __restrict__ idx,
                             const float* __restrict__ W0, const float* __restrict__ b0,
                             float* __restrict__ out, int N) {
  size_t t = (size_t)blockIdx.x * blockDim.x + threadIdx.x;  // over NB*128*8*N
  int n = (int)(t % N); size_t r = t / N;
  int k = (int)(r % KNBR); r /= KNBR;
  int o = (int)(r % DIMC); int b = (int)(r / DIMC);
  const float* xb = xyz + (size_t)b * 3 * N;
  int j = idx[((size_t)b * N + n) * KNBR + k];
  float dx = xb[j] - xb[n];
  float dy = xb[N + j] - xb[N + n];
  float dz = xb[2 * N + j] - xb[2 * N + n];
  out[t] = W0[o * 3 + 0] * dx + W0[o * 3 + 1] * dy + W0[o * 3 + 2] * dz + b0[o];
}

// ---------------- per-(b,c) partial sum/sumsq ----------------
__global__ void stats_kernel(const float* __restrict__ x, int R, float2* __restrict__ part) {
  int c = blockIdx.x & 127, b = blockIdx.x >> 7;
  const float* px = x + ((size_t)(b * DIMC + c)) * R;
  float s = 0.f, s2 = 0.f;
  for (int i = threadIdx.x; i < R; i += 256) { float v = px[i]; s += v; s2 += v * v; }
#pragma unroll
  for (int off = 32; off; off >>= 1) { s += __shfl_down(s, off, 64); s2 += __shfl_down(s2, off, 64); }
  __shared__ float rs[4], rq[4];
  int w = threadIdx.x >> 6;
  if ((threadIdx.x & 63) == 0) { rs[w] = s; rq[w] = s2; }
  __syncthreads();
  if (threadIdx.x == 0)
    part[blockIdx.x] = make_float2(rs[0] + rs[1] + rs[2] + rs[3], rq[0] + rq[1] + rq[2] + rq[3]);
}

// ---------------- BN finalize: scale/shift per channel ----------------
__global__ void finalize_kernel(const float2* __restrict__ part, float cntInv,
                                const float* __restrict__ gamma, const float* __restrict__ beta,
                                float2* __restrict__ ss) {
  int c = threadIdx.x;  // 128 threads
  float s = 0.f, s2 = 0.f;
  for (int b = 0; b < NB; b++) { float2 v = part[b * DIMC + c]; s += v.x; s2 += v.y; }
  float mean = s * cntInv;
  float var = s2 * cntInv - mean * mean;
  float sc = gamma[c] * rsqrtf(var + 1e-5f);
  ss[c] = make_float2(sc, beta[c] - mean * sc);
}

// ---------------- fused GEMM: Y = alpha*(W @ f(X)) + bias [+ Y]  ----------------
// f(X) = relu(X*scale+shift) if ss != null else X.  W: 128x128 row-major [o][c].
// X/Y layout: [b][c][R] with per-batch channel stride R.
__global__ __launch_bounds__(256) void gemm_kernel(
    const float* __restrict__ X, const float2* __restrict__ ss,
    const float* __restrict__ W, const float* __restrict__ bias,
    float* __restrict__ Y, int R, float alpha, int addShortcut) {
  __shared__ float Wl[DIMC][64];
  __shared__ float Xl[64][68];
  int b = blockIdx.y;
  int r0 = blockIdx.x * 64;
  int cg = threadIdx.x & 15, rg = threadIdx.x >> 4;
  float acc[8][4] = {};
  const float* Xb = X + (size_t)b * DIMC * R;
  for (int kc = 0; kc < DIMC; kc += 64) {
    __syncthreads();
    for (int i = threadIdx.x; i < 2048; i += 256) {          // W chunk 128x64
      int o = i >> 4, c4 = (i & 15) << 2;
      *(float4*)&Wl[o][c4] = *(const float4*)&W[o * DIMC + kc + c4];
    }
    for (int i = threadIdx.x; i < 1024; i += 256) {          // X chunk 64x64
      int c = i >> 4, c4 = (i & 15) << 2;
      float4 v = *(const float4*)&Xb[(size_t)(kc + c) * R + r0 + c4];
      if (ss) {
        float2 t = ss[kc + c];
        v.x = fmaxf(v.x * t.x + t.y, 0.f); v.y = fmaxf(v.y * t.x + t.y, 0.f);
        v.z = fmaxf(v.z * t.x + t.y, 0.f); v.w = fmaxf(v.w * t.x + t.y, 0.f);
      }
      *(float4*)&Xl[c][c4] = v;
    }
    __syncthreads();
#pragma unroll
    for (int c0 = 0; c0 < 64; c0 += 4) {
      float4 xv0 = *(float4*)&Xl[c0 + 0][cg * 4];
      float4 xv1 = *(float4*)&Xl[c0 + 1][cg * 4];
      float4 xv2 = *(float4*)&Xl[c0 + 2][cg * 4];
      float4 xv3 = *(float4*)&Xl[c0 + 3][cg * 4];
#pragma unroll
      for (int r = 0; r < 8; r++) {
        float4 wv = *(float4*)&Wl[rg * 8 + r][c0];
        acc[r][0] += wv.x * xv0.x; acc[r][1] += wv.x * xv0.y; acc[r][2] += wv.x * xv0.z; acc[r][3] += wv.x * xv0.w;
        acc[r][0] += wv.y * xv1.x; acc[r][1] += wv.y * xv1.y; acc[r][2] += wv.y * xv1.z; acc[r][3] += wv.y * xv1.w;
        acc[r][0] += wv.z * xv2.x; acc[r][1] += wv.z * xv2.y; acc[r][2] += wv.z * xv2.z; acc[r][3] += wv.z * xv2.w;
        acc[r][0] += wv.w * xv3.x; acc[r][1] += wv.w * xv3.y; acc[r][2] += wv.w * xv3.z; acc[r][3] += wv.w * xv3.w;
      }
    }
  }
#pragma unroll
  for (int r = 0; r < 8; r++) {
    int o = rg * 8 + r;
    float bi = bias[o];
    float4 v;
    v.x = acc[r][0] * alpha + bi; v.y = acc[r][1] * alpha + bi;
    v.z = acc[r][2] * alpha + bi; v.w = acc[r][3] * alpha + bi;
    size_t off = ((size_t)b * DIMC + o) * R + r0 + cg * 4;
    if (addShortcut) {
      float4 sv = *(const float4*)&Y[off];
      v.x += sv.x; v.y += sv.y; v.z += sv.z; v.w += sv.w;
    }
    *(float4*)&Y[off] = v;
  }
}

// ---------------- featurenet epilogue: max over k of relu(bn(x)) ----------------
__global__ void maxk_kernel(const float* __restrict__ x, const float2* __restrict__ ss,
                            float* __restrict__ out, int N) {
  size_t t = (size_t)blockIdx.x * blockDim.x + threadIdx.x;  // over NB*128*N
  int n = (int)(t % N); size_t r = t / N; int o = (int)(r % DIMC); int b = (int)(r / DIMC);
  const float* p = x + ((size_t)(b * DIMC + o)) * KNBR * N + n;
  float2 s = ss[o];
  float m = 0.f;  // relu values are >= 0
#pragma unroll
  for (int k = 0; k < KNBR; k++) { float v = p[(size_t)k * N] * s.x + s.y; m = fmaxf(m, v); }
  out[t] = m;
}

// ---------------- res: p = relu(bn(points)); agg = p + sum_k p[nbr] ----------------
__global__ void agg_kernel(const float* __restrict__ pts, const float2* __restrict__ ss,
                           const int* __restrict__ idx, float* __restrict__ p,
                           float* __restrict__ agg, int N) {
  int n = blockIdx.x * 256 + threadIdx.x;
  int c0 = blockIdx.y * 4;
  int b = blockIdx.z;
  const int* ib = idx + ((size_t)b * N + n) * KNBR;
  int j[KNBR];
#pragma unroll
  for (int k = 0; k < KNBR; k++) j[k] = ib[k];
#pragma unroll
  for (int ci = 0; ci < 4; ci++) {
    int c = c0 + ci;
    const float* row = pts + ((size_t)b * DIMC + c) * N;
    float2 s = ss[c];
    float pv = fmaxf(row[n] * s.x + s.y, 0.f);
    float sum = pv;
#pragma unroll
    for (int k = 0; k < KNBR; k++) sum += fmaxf(row[j[k]] * s.x + s.y, 0.f);
    p[((size_t)b * DIMC + c) * N + n] = pv;
    agg[((size_t)b * DIMC + c) * N + n] = sum;
  }
}

// ---------------- unpool: new_xyz[b][d][u*N+n] = (Wc.p + Wn.s + bc + 8*bn)/9 + xyz ----------------
__global__ void newxyz_kernel(const float* __restrict__ p, const float* __restrict__ agg,
                              const float* __restrict__ Wc, const float* __restrict__ bc,
                              const float* __restrict__ Wn, const float* __restrict__ bn_,
                              const float* __restrict__ xyzc, float* __restrict__ out, int N) {
  int n = blockIdx.x * 256 + threadIdx.x;
  int b = blockIdx.y;
  float acc[6] = {};
  const float* pb = p + (size_t)b * DIMC * N + n;
  const float* ab = agg + (size_t)b * DIMC * N + n;
  for (int c = 0; c < DIMC; c++) {
    float pv = pb[(size_t)c * N];
    float sv = ab[(size_t)c * N] - pv;
#pragma unroll
    for (int jj = 0; jj < 6; jj++) acc[jj] += Wc[jj * DIMC + c] * pv + Wn[jj * DIMC + c] * sv;
  }
#pragma unroll
  for (int jj = 0; jj < 6; jj++) {
    float v = (acc[jj] + bc[jj] + 8.f * bn_[jj]) * (1.f / 9.f);
    int d = jj >> 1, u = jj & 1;
    out[((size_t)b * 3 + d) * (2 * N) + (size_t)u * N + n] = v + xyzc[((size_t)b * 3 + d) * N + n];
  }
}

// ---------------- interp: mean over k of gathered points ----------------
__global__ void gathermean_kernel(const float* __restrict__ pts, const int* __restrict__ idx,
                                  float* __restrict__ out, int Nin, int M) {
  int m = blockIdx.x * 256 + threadIdx.x;
  int c0 = blockIdx.y * 4, b = blockIdx.z;
  const int* ib = idx + ((size_t)b * M + m) * KNBR;
  int j[KNBR];
#pragma unroll
  for (int k = 0; k < KNBR; k++) j[k] = ib[k];
#pragma unroll
  for (int ci = 0; ci < 4; ci++) {
    int c = c0 + ci;
    const float* row = pts + ((size_t)b * DIMC + c) * Nin;
    float s = 0.f;
#pragma unroll
    for (int k = 0; k < KNBR; k++) s += row[j[k]];
    out[((size_t)b * DIMC + c) * M + m] = s * 0.125f;
  }
}

extern "C" void kernel_launch(void* const* d_in, const int* in_sizes, int n_in,
                              void* d_out, int out_size, void* d_ws, size_t ws_size,
                              hipStream_t stream) {
  const float* xyz    = (const float*)d_in[0];
  const float* fn_W0  = (const float*)d_in[1];
  const float* fn_b0  = (const float*)d_in[2];
  const float* fn_W   = (const float*)d_in[3];
  const float* fn_b   = (const float*)d_in[4];
  const float* fn_bng = (const float*)d_in[5];
  const float* fn_bnb = (const float*)d_in[6];
  const float* rb_bng = (const float*)d_in[7];
  const float* rb_bnb = (const float*)d_in[8];
  const float* rb_W   = (const float*)d_in[9];
  const float* rb_b   = (const float*)d_in[10];
  const float* rb_cW  = (const float*)d_in[11];
  const float* rb_cb  = (const float*)d_in[12];
  const float* rb_nW  = (const float*)d_in[13];
  const float* rb_nb  = (const float*)d_in[14];
  float* out = (float*)d_out;

  const int N1 = 2048, N2 = 4096;
  char* ws = (char*)d_ws;
  float* A    = (float*)ws;                         // 64 MiB: (8,128,8,2048) f32
  float* Bbuf = (float*)(ws + ((size_t)64 << 20));  // 64 MiB
  char* tail = ws + ((size_t)128 << 20);
  int* idx1 = (int*)tail;   tail += (size_t)NB * N1 * KNBR * 4;
  int* idxI = (int*)tail;   tail += (size_t)NB * N2 * KNBR * 4;
  int* idx2 = (int*)tail;   tail += (size_t)NB * N2 * KNBR * 4;
  float* nx1 = (float*)tail; tail += (size_t)NB * 3 * N2 * 4;
  float2* part = (float2*)tail; tail += 1024 * sizeof(float2);
  float2* ssb  = (float2*)tail; tail += 128 * sizeof(float2);

  const size_t SZ1 = (size_t)NB * DIMC * N1;  // 2M floats
  const size_t SZ2 = (size_t)NB * DIMC * N2;  // 4M floats
  float* pts1 = Bbuf;             // after featurenet, Bbuf is free
  float* p1   = Bbuf + SZ1;
  float* agg1 = Bbuf + 2 * SZ1;
  float* pts2 = A;                // after featurenet+gathermean, A is free
  float* p2   = A + SZ2;
  float* agg2 = A + 2 * SZ2;

  // ---------- featurenet ----------
  knn_kernel<true><<<dim3(N1 / 64, NB), 64, 0, stream>>>(xyz, xyz, N1, N1, idx1);
  conv0_kernel<<<(NB * DIMC * KNBR * N1) / 256, 256, 0, stream>>>(xyz, idx1, fn_W0, fn_b0, A, N1);
  int Rf = KNBR * N1;  // 16384
  stats_kernel<<<1024, 256, 0, stream>>>(A, Rf, part);
  finalize_kernel<<<1, 128, 0, stream>>>(part, 1.f / (NB * (float)Rf), fn_bng, fn_bnb, ssb);
  gemm_kernel<<<dim3(Rf / 64, NB), 256, 0, stream>>>(A, ssb, fn_W, fn_b, Bbuf, Rf, 1.f, 0);
  stats_kernel<<<1024, 256, 0, stream>>>(Bbuf, Rf, part);
  finalize_kernel<<<1, 128, 0, stream>>>(part, 1.f / (NB * (float)Rf), fn_bng + 128, fn_bnb + 128, ssb);
  gemm_kernel<<<dim3(Rf / 64, NB), 256, 0, stream>>>(Bbuf, ssb, fn_W + 16384, fn_b + 128, A, Rf, 1.f, 0);
  stats_kernel<<<1024, 256, 0, stream>>>(A, Rf, part);
  finalize_kernel<<<1, 128, 0, stream>>>(part, 1.f / (NB * (float)Rf), fn_bng + 256, fn_bnb + 256, ssb);
  maxk_kernel<<<(NB * DIMC * N1) / 256, 256, 0, stream>>>(A, ssb, pts1, N1);

  // ---------- stage 0 (N=2048, reuse idx1 since xyz identical) ----------
  for (int i = 0; i < 12; i++) {
    stats_kernel<<<1024, 256, 0, stream>>>(pts1, N1, part);
    finalize_kernel<<<1, 128, 0, stream>>>(part, 1.f / (NB * (float)N1),
                                           rb_bng + i * 128, rb_bnb + i * 128, ssb);
    agg_kernel<<<dim3(N1 / 256, 32, NB), 256, 0, stream>>>(pts1, ssb, idx1, p1, agg1, N1);
    gemm_kernel<<<dim3(N1 / 64, NB), 256, 0, stream>>>(agg1, nullptr, rb_W + (size_t)i * 16384,
                                                       rb_b + i * 128, pts1, N1, 1.f / 9.f, 1);
  }
  newxyz_kernel<<<dim3(N1 / 256, NB), 256, 0, stream>>>(p1, agg1, rb_cW, rb_cb, rb_nW, rb_nb,
                                                        xyz, nx1, N1);

  // ---------- interp to 4096 pts ----------
  knn_kernel<false><<<dim3(N2 / 64, NB), 64, 0, stream>>>(xyz, nx1, N1, N2, idxI);
  gathermean_kernel<<<dim3(N2 / 256, 32, NB), 256, 0, stream>>>(pts1, idxI, pts2, N1, N2);
  knn_kernel<true><<<dim3(N2 / 64, NB), 64, 0, stream>>>(nx1, nx1, N2, N2, idx2);

  // ---------- stage 1 (N=4096) ----------
  for (int i = 0; i < 12; i++) {
    stats_kernel<<<1024, 256, 0, stream>>>(pts2, N2, part);
    finalize_kernel<<<1, 128, 0, stream>>>(part, 1.f / (NB * (float)N2),
                                           rb_bng + (12 + i) * 128, rb_bnb + (12 + i) * 128, ssb);
    agg_kernel<<<dim3(N2 / 256, 32, NB), 256, 0, stream>>>(pts2, ssb, idx2, p2, agg2, N2);
    gemm_kernel<<<dim3(N2 / 64, NB), 256, 0, stream>>>(agg2, nullptr, rb_W + (size_t)(12 + i) * 16384,
                                                       rb_b + (12 + i) * 128, pts2, N2, 1.f / 9.f, 1);
  }
  newxyz_kernel<<<dim3(N2 / 256, NB), 256, 0, stream>>>(p2, agg2, rb_cW + 768, rb_cb + 6,
                                                        rb_nW + 768, rb_nb + 6, nx1, out, N2);
}

// Round 2
// 2163.345 us; speedup vs baseline: 1.4112x; 1.4112x over previous
//
#include <hip/hip_runtime.h>

#define NB 8        // batch
#define DIMC 128
#define KNBR 8

// ---------------- KNN: wave-per-query, lane-split refs, register top-8 + wave merge ----------------
#define KTILE 1024
template<bool EXCL>
__global__ __launch_bounds__(256) void knn_kernel(const float* __restrict__ ref,
                                                  const float* __restrict__ qry,
                                                  int Nr, int Nq, int* __restrict__ idx_out) {
  __shared__ float4 sref[KTILE];  // x,y,z,r2 : 16 KB
  int b = blockIdx.y;
  int wid = threadIdx.x >> 6, lane = threadIdx.x & 63;
  int qi = blockIdx.x * 4 + wid;
  const float* rb = ref + (size_t)b * 3 * Nr;
  const float* qb = qry + (size_t)b * 3 * Nq;
  float m2qx = -2.f * qb[qi], m2qy = -2.f * qb[Nq + qi], m2qz = -2.f * qb[2 * Nq + qi];
  // q^2 term omitted: constant per query, ranking-invariant.
  float bd[KNBR]; int bi[KNBR];
#pragma unroll
  for (int t = 0; t < KNBR; t++) { bd[t] = 3.4e38f; bi[t] = 0; }
  for (int tile = 0; tile < Nr; tile += KTILE) {
    int cnt = min(KTILE, Nr - tile);
    __syncthreads();
    for (int j = threadIdx.x; j < cnt; j += 256) {
      float rx = rb[tile + j], ry = rb[Nr + tile + j], rz = rb[2 * Nr + tile + j];
      sref[j] = make_float4(rx, ry, rz, rx * rx + ry * ry + rz * rz);
    }
    __syncthreads();
    for (int j = lane; j < cnt; j += 64) {
      int gj = tile + j;
      if (EXCL && gj == qi) continue;
      float4 r = sref[j];
      float d = fmaf(m2qx, r.x, fmaf(m2qy, r.y, fmaf(m2qz, r.z, r.w)));
      if (d < bd[KNBR - 1]) {
        bd[KNBR - 1] = d; bi[KNBR - 1] = gj;
#pragma unroll
        for (int t = KNBR - 1; t > 0; t--)
          if (bd[t] < bd[t - 1]) {
            float td = bd[t]; bd[t] = bd[t - 1]; bd[t - 1] = td;
            int ti = bi[t]; bi[t] = bi[t - 1]; bi[t - 1] = ti;
          }
      }
    }
  }
  // 8-round wave merge: min over lanes of sorted heads, winner pops (static indices only)
  int myout = 0;
#pragma unroll
  for (int r = 0; r < KNBR; r++) {
    float d = bd[0]; int ix = bi[0];
#pragma unroll
    for (int off = 32; off; off >>= 1) {
      float d2 = __shfl_xor(d, off);
      int i2 = __shfl_xor(ix, off);
      if (d2 < d || (d2 == d && i2 < ix)) { d = d2; ix = i2; }
    }
    if (bd[0] == d && bi[0] == ix) {   // unique: each ref idx lives in exactly one lane
#pragma unroll
      for (int t = 0; t < KNBR - 1; t++) { bd[t] = bd[t + 1]; bi[t] = bi[t + 1]; }
      bd[KNBR - 1] = 3.4e38f;
    }
    if (lane == r) myout = ix;
  }
  if (lane < KNBR) idx_out[((size_t)b * Nq + qi) * KNBR + lane] = myout;
}

// ---------------- featurenet conv0: W0(128x3) applied to (gathered xyz - center) ----------------
__global__ void conv0_kernel(const float* __restrict__ xyz, const int* __restrict__ idx,
                             const float* __restrict__ W0, const float* __restrict__ b0,
                             float* __restrict__ out, int N) {
  size_t t = (size_t)blockIdx.x * blockDim.x + threadIdx.x;  // over NB*128*8*N
  int n = (int)(t % N); size_t r = t / N;
  int k = (int)(r % KNBR); r /= KNBR;
  int o = (int)(r % DIMC); int b = (int)(r / DIMC);
  const float* xb = xyz + (size_t)b * 3 * N;
  int j = idx[((size_t)b * N + n) * KNBR + k];
  float dx = xb[j] - xb[n];
  float dy = xb[N + j] - xb[N + n];
  float dz = xb[2 * N + j] - xb[2 * N + n];
  out[t] = W0[o * 3 + 0] * dx + W0[o * 3 + 1] * dy + W0[o * 3 + 2] * dz + b0[o];
}

// ---------------- per-(b,c) partial sum/sumsq ----------------
__global__ void stats_kernel(const float* __restrict__ x, int R, float2* __restrict__ part) {
  int c = blockIdx.x & 127, b = blockIdx.x >> 7;
  const float* px = x + ((size_t)(b * DIMC + c)) * R;
  float s = 0.f, s2 = 0.f;
  for (int i = threadIdx.x; i < R; i += 256) { float v = px[i]; s += v; s2 += v * v; }
#pragma unroll
  for (int off = 32; off; off >>= 1) { s += __shfl_down(s, off, 64); s2 += __shfl_down(s2, off, 64); }
  __shared__ float rs[4], rq[4];
  int w = threadIdx.x >> 6;
  if ((threadIdx.x & 63) == 0) { rs[w] = s; rq[w] = s2; }
  __syncthreads();
  if (threadIdx.x == 0)
    part[blockIdx.x] = make_float2(rs[0] + rs[1] + rs[2] + rs[3], rq[0] + rq[1] + rq[2] + rq[3]);
}

// ---------------- BN finalize: scale/shift per channel ----------------
__global__ void finalize_kernel(const float2* __restrict__ part, float cntInv,
                                const float* __restrict__ gamma, const float* __restrict__ beta,
                                float2* __restrict__ ss) {
  int c = threadIdx.x;  // 128 threads
  float s = 0.f, s2 = 0.f;
  for (int b = 0; b < NB; b++) { float2 v = part[b * DIMC + c]; s += v.x; s2 += v.y; }
  float mean = s * cntInv;
  float var = s2 * cntInv - mean * mean;
  float sc = gamma[c] * rsqrtf(var + 1e-5f);
  ss[c] = make_float2(sc, beta[c] - mean * sc);
}

// ---------------- fused GEMM: Y = alpha*(W @ f(X)) + bias [+ Y]  ----------------
// f(X) = relu(X*scale+shift) if ss != null else X.  W: 128x128 row-major [o][c].
// X/Y layout: [b][c][R] with per-batch channel stride R.
__global__ __launch_bounds__(256) void gemm_kernel(
    const float* __restrict__ X, const float2* __restrict__ ss,
    const float* __restrict__ W, const float* __restrict__ bias,
    float* __restrict__ Y, int R, float alpha, int addShortcut) {
  __shared__ float Wl[DIMC][64];
  __shared__ float Xl[64][68];
  int b = blockIdx.y;
  int r0 = blockIdx.x * 64;
  int cg = threadIdx.x & 15, rg = threadIdx.x >> 4;
  float acc[8][4] = {};
  const float* Xb = X + (size_t)b * DIMC * R;
  for (int kc = 0; kc < DIMC; kc += 64) {
    __syncthreads();
    for (int i = threadIdx.x; i < 2048; i += 256) {          // W chunk 128x64
      int o = i >> 4, c4 = (i & 15) << 2;
      *(float4*)&Wl[o][c4] = *(const float4*)&W[o * DIMC + kc + c4];
    }
    for (int i = threadIdx.x; i < 1024; i += 256) {          // X chunk 64x64
      int c = i >> 4, c4 = (i & 15) << 2;
      float4 v = *(const float4*)&Xb[(size_t)(kc + c) * R + r0 + c4];
      if (ss) {
        float2 t = ss[kc + c];
        v.x = fmaxf(v.x * t.x + t.y, 0.f); v.y = fmaxf(v.y * t.x + t.y, 0.f);
        v.z = fmaxf(v.z * t.x + t.y, 0.f); v.w = fmaxf(v.w * t.x + t.y, 0.f);
      }
      *(float4*)&Xl[c][c4] = v;
    }
    __syncthreads();
#pragma unroll
    for (int c0 = 0; c0 < 64; c0 += 4) {
      float4 xv0 = *(float4*)&Xl[c0 + 0][cg * 4];
      float4 xv1 = *(float4*)&Xl[c0 + 1][cg * 4];
      float4 xv2 = *(float4*)&Xl[c0 + 2][cg * 4];
      float4 xv3 = *(float4*)&Xl[c0 + 3][cg * 4];
#pragma unroll
      for (int r = 0; r < 8; r++) {
        float4 wv = *(float4*)&Wl[rg * 8 + r][c0];
        acc[r][0] += wv.x * xv0.x; acc[r][1] += wv.x * xv0.y; acc[r][2] += wv.x * xv0.z; acc[r][3] += wv.x * xv0.w;
        acc[r][0] += wv.y * xv1.x; acc[r][1] += wv.y * xv1.y; acc[r][2] += wv.y * xv1.z; acc[r][3] += wv.y * xv1.w;
        acc[r][0] += wv.z * xv2.x; acc[r][1] += wv.z * xv2.y; acc[r][2] += wv.z * xv2.z; acc[r][3] += wv.z * xv2.w;
        acc[r][0] += wv.w * xv3.x; acc[r][1] += wv.w * xv3.y; acc[r][2] += wv.w * xv3.z; acc[r][3] += wv.w * xv3.w;
      }
    }
  }
#pragma unroll
  for (int r = 0; r < 8; r++) {
    int o = rg * 8 + r;
    float bi = bias[o];
    float4 v;
    v.x = acc[r][0] * alpha + bi; v.y = acc[r][1] * alpha + bi;
    v.z = acc[r][2] * alpha + bi; v.w = acc[r][3] * alpha + bi;
    size_t off = ((size_t)b * DIMC + o) * R + r0 + cg * 4;
    if (addShortcut) {
      float4 sv = *(const float4*)&Y[off];
      v.x += sv.x; v.y += sv.y; v.z += sv.z; v.w += sv.w;
    }
    *(float4*)&Y[off] = v;
  }
}

// ---------------- featurenet epilogue: max over k of relu(bn(x)) ----------------
__global__ void maxk_kernel(const float* __restrict__ x, const float2* __restrict__ ss,
                            float* __restrict__ out, int N) {
  size_t t = (size_t)blockIdx.x * blockDim.x + threadIdx.x;  // over NB*128*N
  int n = (int)(t % N); size_t r = t / N; int o = (int)(r % DIMC); int b = (int)(r / DIMC);
  const float* p = x + ((size_t)(b * DIMC + o)) * KNBR * N + n;
  float2 s = ss[o];
  float m = 0.f;  // relu values are >= 0
#pragma unroll
  for (int k = 0; k < KNBR; k++) { float v = p[(size_t)k * N] * s.x + s.y; m = fmaxf(m, v); }
  out[t] = m;
}

// ---------------- res: p = relu(bn(points)); agg = p + sum_k p[nbr] ----------------
__global__ void agg_kernel(const float* __restrict__ pts, const float2* __restrict__ ss,
                           const int* __restrict__ idx, float* __restrict__ p,
                           float* __restrict__ agg, int N) {
  int n = blockIdx.x * 256 + threadIdx.x;
  int c0 = blockIdx.y * 4;
  int b = blockIdx.z;
  const int* ib = idx + ((size_t)b * N + n) * KNBR;
  int j[KNBR];
#pragma unroll
  for (int k = 0; k < KNBR; k++) j[k] = ib[k];
#pragma unroll
  for (int ci = 0; ci < 4; ci++) {
    int c = c0 + ci;
    const float* row = pts + ((size_t)b * DIMC + c) * N;
    float2 s = ss[c];
    float pv = fmaxf(row[n] * s.x + s.y, 0.f);
    float sum = pv;
#pragma unroll
    for (int k = 0; k < KNBR; k++) sum += fmaxf(row[j[k]] * s.x + s.y, 0.f);
    p[((size_t)b * DIMC + c) * N + n] = pv;
    agg[((size_t)b * DIMC + c) * N + n] = sum;
  }
}

// ---------------- unpool: new_xyz[b][d][u*N+n] = (Wc.p + Wn.s + bc + 8*bn)/9 + xyz ----------------
__global__ void newxyz_kernel(const float* __restrict__ p, const float* __restrict__ agg,
                              const float* __restrict__ Wc, const float* __restrict__ bc,
                              const float* __restrict__ Wn, const float* __restrict__ bn_,
                              const float* __restrict__ xyzc, float* __restrict__ out, int N) {
  int n = blockIdx.x * 256 + threadIdx.x;
  int b = blockIdx.y;
  float acc[6] = {};
  const float* pb = p + (size_t)b * DIMC * N + n;
  const float* ab = agg + (size_t)b * DIMC * N + n;
  for (int c = 0; c < DIMC; c++) {
    float pv = pb[(size_t)c * N];
    float sv = ab[(size_t)c * N] - pv;
#pragma unroll
    for (int jj = 0; jj < 6; jj++) acc[jj] += Wc[jj * DIMC + c] * pv + Wn[jj * DIMC + c] * sv;
  }
#pragma unroll
  for (int jj = 0; jj < 6; jj++) {
    float v = (acc[jj] + bc[jj] + 8.f * bn_[jj]) * (1.f / 9.f);
    int d = jj >> 1, u = jj & 1;
    out[((size_t)b * 3 + d) * (2 * N) + (size_t)u * N + n] = v + xyzc[((size_t)b * 3 + d) * N + n];
  }
}

// ---------------- interp: mean over k of gathered points ----------------
__global__ void gathermean_kernel(const float* __restrict__ pts, const int* __restrict__ idx,
                                  float* __restrict__ out, int Nin, int M) {
  int m = blockIdx.x * 256 + threadIdx.x;
  int c0 = blockIdx.y * 4, b = blockIdx.z;
  const int* ib = idx + ((size_t)b * M + m) * KNBR;
  int j[KNBR];
#pragma unroll
  for (int k = 0; k < KNBR; k++) j[k] = ib[k];
#pragma unroll
  for (int ci = 0; ci < 4; ci++) {
    int c = c0 + ci;
    const float* row = pts + ((size_t)b * DIMC + c) * Nin;
    float s = 0.f;
#pragma unroll
    for (int k = 0; k < KNBR; k++) s += row[j[k]];
    out[((size_t)b * DIMC + c) * M + m] = s * 0.125f;
  }
}

extern "C" void kernel_launch(void* const* d_in, const int* in_sizes, int n_in,
                              void* d_out, int out_size, void* d_ws, size_t ws_size,
                              hipStream_t stream) {
  const float* xyz    = (const float*)d_in[0];
  const float* fn_W0  = (const float*)d_in[1];
  const float* fn_b0  = (const float*)d_in[2];
  const float* fn_W   = (const float*)d_in[3];
  const float* fn_b   = (const float*)d_in[4];
  const float* fn_bng = (const float*)d_in[5];
  const float* fn_bnb = (const float*)d_in[6];
  const float* rb_bng = (const float*)d_in[7];
  const float* rb_bnb = (const float*)d_in[8];
  const float* rb_W   = (const float*)d_in[9];
  const float* rb_b   = (const float*)d_in[10];
  const float* rb_cW  = (const float*)d_in[11];
  const float* rb_cb  = (const float*)d_in[12];
  const float* rb_nW  = (const float*)d_in[13];
  const float* rb_nb  = (const float*)d_in[14];
  float* out = (float*)d_out;

  const int N1 = 2048, N2 = 4096;
  char* ws = (char*)d_ws;
  float* A    = (float*)ws;                         // 64 MiB: (8,128,8,2048) f32
  float* Bbuf = (float*)(ws + ((size_t)64 << 20));  // 64 MiB
  char* tail = ws + ((size_t)128 << 20);
  int* idx1 = (int*)tail;   tail += (size_t)NB * N1 * KNBR * 4;
  int* idxI = (int*)tail;   tail += (size_t)NB * N2 * KNBR * 4;
  int* idx2 = (int*)tail;   tail += (size_t)NB * N2 * KNBR * 4;
  float* nx1 = (float*)tail; tail += (size_t)NB * 3 * N2 * 4;
  float2* part = (float2*)tail; tail += 1024 * sizeof(float2);
  float2* ssb  = (float2*)tail; tail += 128 * sizeof(float2);

  const size_t SZ1 = (size_t)NB * DIMC * N1;  // 2M floats
  const size_t SZ2 = (size_t)NB * DIMC * N2;  // 4M floats
  float* pts1 = Bbuf;             // after featurenet, Bbuf is free
  float* p1   = Bbuf + SZ1;
  float* agg1 = Bbuf + 2 * SZ1;
  float* pts2 = A;                // after featurenet+gathermean, A is free
  float* p2   = A + SZ2;
  float* agg2 = A + 2 * SZ2;

  // ---------- featurenet ----------
  knn_kernel<true><<<dim3(N1 / 4, NB), 256, 0, stream>>>(xyz, xyz, N1, N1, idx1);
  conv0_kernel<<<(NB * DIMC * KNBR * N1) / 256, 256, 0, stream>>>(xyz, idx1, fn_W0, fn_b0, A, N1);
  int Rf = KNBR * N1;  // 16384
  stats_kernel<<<1024, 256, 0, stream>>>(A, Rf, part);
  finalize_kernel<<<1, 128, 0, stream>>>(part, 1.f / (NB * (float)Rf), fn_bng, fn_bnb, ssb);
  gemm_kernel<<<dim3(Rf / 64, NB), 256, 0, stream>>>(A, ssb, fn_W, fn_b, Bbuf, Rf, 1.f, 0);
  stats_kernel<<<1024, 256, 0, stream>>>(Bbuf, Rf, part);
  finalize_kernel<<<1, 128, 0, stream>>>(part, 1.f / (NB * (float)Rf), fn_bng + 128, fn_bnb + 128, ssb);
  gemm_kernel<<<dim3(Rf / 64, NB), 256, 0, stream>>>(Bbuf, ssb, fn_W + 16384, fn_b + 128, A, Rf, 1.f, 0);
  stats_kernel<<<1024, 256, 0, stream>>>(A, Rf, part);
  finalize_kernel<<<1, 128, 0, stream>>>(part, 1.f / (NB * (float)Rf), fn_bng + 256, fn_bnb + 256, ssb);
  maxk_kernel<<<(NB * DIMC * N1) / 256, 256, 0, stream>>>(A, ssb, pts1, N1);

  // ---------- stage 0 (N=2048, reuse idx1 since xyz identical) ----------
  for (int i = 0; i < 12; i++) {
    stats_kernel<<<1024, 256, 0, stream>>>(pts1, N1, part);
    finalize_kernel<<<1, 128, 0, stream>>>(part, 1.f / (NB * (float)N1),
                                           rb_bng + i * 128, rb_bnb + i * 128, ssb);
    agg_kernel<<<dim3(N1 / 256, 32, NB), 256, 0, stream>>>(pts1, ssb, idx1, p1, agg1, N1);
    gemm_kernel<<<dim3(N1 / 64, NB), 256, 0, stream>>>(agg1, nullptr, rb_W + (size_t)i * 16384,
                                                       rb_b + i * 128, pts1, N1, 1.f / 9.f, 1);
  }
  newxyz_kernel<<<dim3(N1 / 256, NB), 256, 0, stream>>>(p1, agg1, rb_cW, rb_cb, rb_nW, rb_nb,
                                                        xyz, nx1, N1);

  // ---------- interp to 4096 pts ----------
  knn_kernel<false><<<dim3(N2 / 4, NB), 256, 0, stream>>>(xyz, nx1, N1, N2, idxI);
  gathermean_kernel<<<dim3(N2 / 256, 32, NB), 256, 0, stream>>>(pts1, idxI, pts2, N1, N2);
  knn_kernel<true><<<dim3(N2 / 4, NB), 256, 0, stream>>>(nx1, nx1, N2, N2, idx2);

  // ---------- stage 1 (N=4096) ----------
  for (int i = 0; i < 12; i++) {
    stats_kernel<<<1024, 256, 0, stream>>>(pts2, N2, part);
    finalize_kernel<<<1, 128, 0, stream>>>(part, 1.f / (NB * (float)N2),
                                           rb_bng + (12 + i) * 128, rb_bnb + (12 + i) * 128, ssb);
    agg_kernel<<<dim3(N2 / 256, 32, NB), 256, 0, stream>>>(pts2, ssb, idx2, p2, agg2, N2);
    gemm_kernel<<<dim3(N2 / 64, NB), 256, 0, stream>>>(agg2, nullptr, rb_W + (size_t)(12 + i) * 16384,
                                                       rb_b + (12 + i) * 128, pts2, N2, 1.f / 9.f, 1);
  }
  newxyz_kernel<<<dim3(N2 / 256, NB), 256, 0, stream>>>(p2, agg2, rb_cW + 768, rb_cb + 6,
                                                        rb_nW + 768, rb_nb + 6, nx1, out, N2);
}